// Round 1
// baseline (530.819 us; speedup 1.0000x reference)
//
#include <hip/hip_runtime.h>

// Problem constants (fixed by the harness setup):
//   x: (B, N+1, D) fp32, significance: (B, N) fp32, keep_tokens K=1024
constexpr int B    = 32;
constexpr int NTOK = 4096;      // tokens per batch excluding cls
constexpr int D    = 768;
constexpr int K    = 1024;
constexpr int D4   = D / 4;     // 192 float4 per row
constexpr int SORT_THREADS = 1024;

// Map float bits to unsigned so unsigned compare == float compare (total order).
__device__ __forceinline__ unsigned monotone_u32(float f) {
  unsigned u = __float_as_uint(f);
  return (u & 0x80000000u) ? ~u : (u | 0x80000000u);
}

// One block per batch. Bitonic-sort 4096 packed keys in LDS ascending:
//   key = (~monotone(val) << 32) | index
// Ascending key order == descending value order, ties -> smaller index first
// (matches jax.lax.top_k). First K entries are the sorted top-k indices.
__global__ __launch_bounds__(SORT_THREADS)
void topk_sort_kernel(const float* __restrict__ sig, int* __restrict__ idx_out) {
  __shared__ unsigned long long keys[NTOK];
  const int b = blockIdx.x;
  const float* s = sig + (size_t)b * NTOK;

  #pragma unroll
  for (int rep = 0; rep < NTOK / SORT_THREADS; ++rep) {
    int i = threadIdx.x + rep * SORT_THREADS;
    unsigned u = monotone_u32(s[i]);
    keys[i] = ((unsigned long long)(~u) << 32) | (unsigned)i;
  }
  __syncthreads();

  for (int k = 2; k <= NTOK; k <<= 1) {
    for (int j = k >> 1; j > 0; j >>= 1) {
      #pragma unroll
      for (int rep = 0; rep < NTOK / SORT_THREADS; ++rep) {
        int i = threadIdx.x + rep * SORT_THREADS;
        int ixj = i ^ j;
        if (ixj > i) {
          unsigned long long a = keys[i];
          unsigned long long c = keys[ixj];
          // ascending bitonic: region dir from (i & k)
          if ((a > c) == ((i & k) == 0)) { keys[i] = c; keys[ixj] = a; }
        }
      }
      __syncthreads();
    }
  }

  // K == SORT_THREADS: every thread writes one index
  idx_out[b * K + threadIdx.x] = (int)(unsigned)(keys[threadIdx.x] & 0xffffffffu);
}

// One block per output row (b, r). r==0 -> cls row, else gathered token row.
// 192 threads x float4 = 768 floats = one row.
__global__ __launch_bounds__(D4)
void gather_kernel(const float4* __restrict__ x, const int* __restrict__ idx,
                   float4* __restrict__ out) {
  const int blk = blockIdx.x;            // = b * (K+1) + r
  const int b   = blk / (K + 1);
  const int r   = blk - b * (K + 1);
  int src_row = 0;
  if (r != 0) src_row = 1 + idx[b * K + (r - 1)];   // broadcast load
  const size_t src = ((size_t)b * (NTOK + 1) + src_row) * D4 + threadIdx.x;
  const size_t dst = (size_t)blk * D4 + threadIdx.x;
  out[dst] = x[src];
}

extern "C" void kernel_launch(void* const* d_in, const int* in_sizes, int n_in,
                              void* d_out, int out_size, void* d_ws, size_t ws_size,
                              hipStream_t stream) {
  const float* x   = (const float*)d_in[0];
  const float* sig = (const float*)d_in[1];
  // d_in[2] = keep_tokens (device int), fixed at 1024 < NTOK -> always gather path
  int*   idx = (int*)d_ws;               // B*K ints = 128 KB scratch
  float* out = (float*)d_out;

  topk_sort_kernel<<<B, SORT_THREADS, 0, stream>>>(sig, idx);
  gather_kernel<<<B * (K + 1), D4, 0, stream>>>(
      (const float4*)x, idx, (float4*)out);
}

// Round 3
// 492.444 us; speedup vs baseline: 1.0779x; 1.0779x over previous
//
#include <hip/hip_runtime.h>

// x: (B, N+1, D) fp32, significance: (B, N) fp32, keep_tokens K=1024
constexpr int B    = 32;
constexpr int NTOK = 4096;
constexpr int D    = 768;
constexpr int K    = 1024;
constexpr int D4   = D / 4;      // 192 float4 per row
constexpr int CH   = 1024;       // chunk size for stage-A sort

// clang vector type (usable with nontemporal builtins, unlike HIP float4)
typedef float vfloat4 __attribute__((ext_vector_type(4)));

// Map float bits to unsigned so unsigned compare == float compare.
__device__ __forceinline__ unsigned monotone_u32(float f) {
  unsigned u = __float_as_uint(f);
  return (u & 0x80000000u) ? ~u : (u | 0x80000000u);
}

// key = (~monotone(v) << 32) | global_token_idx
// ascending key order == descending value, ties -> smaller index (jax semantics).
__device__ __forceinline__ unsigned long long mkkey(float v, unsigned gidx) {
  return ((unsigned long long)(~monotone_u32(v)) << 32) | gidx;
}

// Stage A: block (b,c) bitonic-sorts its 1024-chunk through k=1024, using the
// GLOBAL element index for direction bits so the result is exactly the state
// of a monolithic 4096 bitonic sort after the k=1024 stage. 128 blocks.
__global__ __launch_bounds__(512)
void chunk_sort(const float* __restrict__ sig, unsigned long long* __restrict__ wsk) {
  __shared__ unsigned long long keys[CH];
  const int b = blockIdx.x >> 2, c = blockIdx.x & 3;
  const float* s = sig + (size_t)b * NTOK + c * CH;

  #pragma unroll
  for (int rep = 0; rep < 2; ++rep) {
    int i = threadIdx.x + rep * 512;
    keys[i] = mkkey(s[i], c * CH + i);
  }
  __syncthreads();

  for (int k = 2; k <= CH; k <<= 1) {
    for (int j = k >> 1; j > 0; j >>= 1) {
      int p = threadIdx.x;                       // 512 pairs, one per thread
      int i = ((p & ~(j - 1)) << 1) | (p & (j - 1));
      int ig = (c << 10) | i;                    // global index (for k=1024 dir bit)
      bool dir = ((ig & k) == 0);
      unsigned long long a = keys[i], d = keys[i | j];
      if ((a > d) == dir) { keys[i] = d; keys[i | j] = a; }
      __syncthreads();
    }
  }

  unsigned long long* o = wsk + (size_t)b * NTOK + c * CH;
  #pragma unroll
  for (int rep = 0; rep < 2; ++rep) {
    int i = threadIdx.x + rep * 512;
    o[i] = keys[i];
  }
}

// Stage B: k=2048 stage (j=1024..1), block (b,h) owns a 2048-half. 64 blocks.
__global__ __launch_bounds__(1024)
void merge2048(unsigned long long* __restrict__ wsk) {
  __shared__ unsigned long long keys[2048];
  const int b = blockIdx.x >> 1, h = blockIdx.x & 1;
  unsigned long long* g = wsk + (size_t)b * NTOK + h * 2048;
  keys[threadIdx.x]        = g[threadIdx.x];
  keys[threadIdx.x + 1024] = g[threadIdx.x + 1024];
  __syncthreads();

  const bool dir = (h == 0);                     // region dir for k=2048
  for (int j = 1024; j > 0; j >>= 1) {
    int p = threadIdx.x;
    int i = ((p & ~(j - 1)) << 1) | (p & (j - 1));
    unsigned long long a = keys[i], d = keys[i | j];
    if ((a > d) == dir) { keys[i] = d; keys[i | j] = a; }
    __syncthreads();
  }

  g[threadIdx.x]        = keys[threadIdx.x];
  g[threadIdx.x + 1024] = keys[threadIdx.x + 1024];
}

// Stage C: k=4096 stage (j=2048..1, all-ascending) + emit top-K indices. 32 blocks.
__global__ __launch_bounds__(1024)
void merge4096_emit(const unsigned long long* __restrict__ wsk, int* __restrict__ idx) {
  __shared__ unsigned long long keys[NTOK];
  const int b = blockIdx.x;
  const unsigned long long* g = wsk + (size_t)b * NTOK;
  #pragma unroll
  for (int rep = 0; rep < 4; ++rep) {
    int i = threadIdx.x + rep * 1024;
    keys[i] = g[i];
  }
  __syncthreads();

  for (int j = 2048; j > 0; j >>= 1) {
    #pragma unroll
    for (int rep = 0; rep < 2; ++rep) {
      int p = threadIdx.x + rep * 1024;
      int i = ((p & ~(j - 1)) << 1) | (p & (j - 1));
      unsigned long long a = keys[i], d = keys[i | j];
      if (a > d) { keys[i] = d; keys[i | j] = a; }
    }
    __syncthreads();
  }

  idx[b * K + threadIdx.x] = (int)(unsigned)(keys[threadIdx.x] & 0xffffffffu);
}

// Gather: one block per output row (b, r); r==0 -> cls row. 192 threads x float4.
// x/out are pure streaming (zero reuse) -> nontemporal; idx stays cached.
__global__ __launch_bounds__(D4)
void gather_kernel(const vfloat4* __restrict__ x, const int* __restrict__ idx,
                   vfloat4* __restrict__ out) {
  const int blk = blockIdx.x;                    // = b * (K+1) + r
  const int b   = blk / (K + 1);
  const int r   = blk - b * (K + 1);
  int src_row = 0;
  if (r != 0) src_row = 1 + idx[b * K + (r - 1)];
  const size_t src = ((size_t)b * (NTOK + 1) + src_row) * D4 + threadIdx.x;
  const size_t dst = (size_t)blk * D4 + threadIdx.x;
  vfloat4 v = __builtin_nontemporal_load(&x[src]);
  __builtin_nontemporal_store(v, &out[dst]);
}

extern "C" void kernel_launch(void* const* d_in, const int* in_sizes, int n_in,
                              void* d_out, int out_size, void* d_ws, size_t ws_size,
                              hipStream_t stream) {
  const float* x   = (const float*)d_in[0];
  const float* sig = (const float*)d_in[1];
  float* out = (float*)d_out;

  // ws layout: [0, 1MB) sort keys, [1MB, +128KB) top-k indices
  unsigned long long* wsk = (unsigned long long*)d_ws;
  int* idx = (int*)((char*)d_ws + (size_t)B * NTOK * sizeof(unsigned long long));

  chunk_sort   <<<B * 4, 512,  0, stream>>>(sig, wsk);
  merge2048    <<<B * 2, 1024, 0, stream>>>(wsk);
  merge4096_emit<<<B,    1024, 0, stream>>>(wsk, idx);
  gather_kernel<<<B * (K + 1), D4, 0, stream>>>((const vfloat4*)x, idx, (vfloat4*)out);
}